// Round 6
// baseline (133.631 us; speedup 1.0000x reference)
//
#include <hip/hip_runtime.h>

// alpha-entmax: TWO-SIDED safeguarded solver on f(tau) = sum (xs-tau)_+^p - 1,
// p = 1/(alpha-1), over the ballot-compacted fixed active set.
//   f >= 1 (left side):  log-Newton  step = ln(f)*f/(p*g)   (exact for dense
//     exponential regime; mild overshoot only, caught by bracket)
//   f <  1 (right side): F-Newton on F = f^(1/p) (convex => jumps back across
//     the root; never stalls like log-Newton does as f->0)  [R4's failure mode]
//   bracket [tlo,thi] from sign(f-1); out-of-bracket or f==0 -> bisect.
// Epilogue: positions recomputed by redoing the deterministic ballot over the
// live xs[] registers; normalized p written to LDS once and gathered -> direct
// coalesced float4 store (no zero/scatter/reread passes, no cidx array).

__device__ __forceinline__ float wave_sum(float v) {
#pragma unroll
  for (int off = 32; off > 0; off >>= 1) v += __shfl_xor(v, off, 64);
  return v;
}
__device__ __forceinline__ float wave_max(float v) {
#pragma unroll
  for (int off = 32; off > 0; off >>= 1) v = fmaxf(v, __shfl_xor(v, off, 64));
  return v;
}

#define MAXIT 12

__global__ __launch_bounds__(256) void entmax_twoside(
    const float* __restrict__ X, const float* __restrict__ A,
    float* __restrict__ O, int nrows) {
  __shared__ float cval[4][1024];   // compacted values; reused for normalized p

  const int lane = threadIdx.x & 63;
  const int wid  = threadIdx.x >> 6;
  const long long row = (long long)blockIdx.x * 4 + wid;
  if (row >= nrows) return;

  const float* xr = X + row * 1024;
  float* orow     = O + row * 1024;

  const int h = (int)((row >> 10) & 15);     // [B,H,Q] flattened, Q=1024
  const float a   = 1.01f + 0.98f * A[h];
  const float am1 = a - 1.0f;                // = 1/p
  const float inv = 1.0f / am1;              // = p in (1.01, 100]
  const float c1  = inv - 1.0f;
  const float c2  = 0.6931471805599453f * am1;  // ln2/p (log-Newton scale)

  // load row, scale by (alpha-1); element 4c+k of lane l = row[c*256 + l*4 + k]
  float xs[16];
#pragma unroll
  for (int c = 0; c < 4; ++c) {
    float4 t = reinterpret_cast<const float4*>(xr)[c * 64 + lane];
    xs[4*c+0] = t.x * am1; xs[4*c+1] = t.y * am1;
    xs[4*c+2] = t.z * am1; xs[4*c+3] = t.w * am1;
  }
  float m = xs[0];
#pragma unroll
  for (int j = 1; j < 16; ++j) m = fmaxf(m, xs[j]);
  m = wave_max(m);
  const float tau0 = m - 1.0f;

  // ---- ballot-compact the fixed active set {xs > tau0} into LDS ----
  int base = 0;
#pragma unroll
  for (int c = 0; c < 4; ++c) {
#pragma unroll
    for (int k = 0; k < 4; ++k) {
      const int j = 4*c + k;
      const bool act = xs[j] > tau0;
      const unsigned long long mk = __ballot(act);
      if (act)
        cval[wid][base + __popcll(mk & ((1ull << lane) - 1ull))] = xs[j];
      base += __popcll(mk);
    }
  }
  const int nact = __builtin_amdgcn_readfirstlane(base);   // >= 1 (the max)
  const int K    = (nact + 63) >> 6;                       // elems per lane
  for (int pos = nact + lane; pos < (K << 6); pos += 64)
    cval[wid][pos] = -3.0e38f;                             // pad: u == 0 forever
  asm volatile("s_waitcnt lgkmcnt(0)" ::: "memory");

  float vals[16];
#pragma unroll
  for (int k = 0; k < 16; ++k)
    if (k < K) vals[k] = cval[wid][lane + (k << 6)];

  // ---- two-sided safeguarded iteration ----
  float tlo = tau0;                                        // f(tlo) >= 1
  float thi = m - __builtin_amdgcn_exp2f(-10.0f * inv);    // f(thi) <= 1
  float tau = tau0;
  float p[16];
  float f = 1.0f;

  for (int it = 0; it < MAXIT; ++it) {
    float fs = 0.0f, gs = 0.0f;
#pragma unroll
    for (int k = 0; k < 16; ++k)
      if (k < K) {                                    // wave-uniform branch
        float u  = fmaxf(vals[k] - tau, 0.0f);
        float l  = __builtin_amdgcn_logf(u);          // log2(0) = -inf
        float e  = __builtin_amdgcn_exp2f(c1 * l);    // u^(p-1); exp2(-inf)=0
        float pe = e * u;                             // u^p
        p[k] = pe; fs += pe; gs += e;
      }
    f = wave_sum(fs);
    const float g = wave_sum(gs);                     // g >= f (u <= 1)

    float tnew;
    if (f > 0.0f) {
      if (f > 1.0f) tlo = tau; else thi = tau;        // bracket update
      if (fabsf(f - 1.0f) <= 1e-6f) break;            // at the root; p,f consistent
      const float lf = __builtin_amdgcn_logf(f);      // log2 f
      float step;
      if (f >= 1.0f) {
        step = lf * c2 * f / g;                       // log-Newton (left side)
      } else {
        const float F = __builtin_amdgcn_exp2f(am1 * lf);  // f^(1/p)
        step = (F - 1.0f) * f / (F * g);              // F-Newton (right side)
      }
      tnew = tau + step;
      if (!(tnew > tlo) || !(tnew < thi))             // out of bracket -> bisect
        tnew = 0.5f * (tlo + thi);
    } else {                                          // f underflowed to 0
      thi = tau;
      tnew = 0.5f * (tlo + thi);
    }
    const float delta = fabsf(tnew - tau);
    tau = tnew;
    if (!(delta > 1e-7f * fmaxf(fabsf(tau), 1.0f))) break;  // wave-uniform
  }

  // ---- epilogue: write normalized p, gather via recomputed positions ----
  const float r = 1.0f / f;                 // sum(p[]) == f from the last eval
#pragma unroll
  for (int k = 0; k < 16; ++k)
    if (k < K) cval[wid][lane + (k << 6)] = p[k] * r;
  asm volatile("s_waitcnt lgkmcnt(0)" ::: "memory");

  base = 0;
#pragma unroll
  for (int c = 0; c < 4; ++c) {
    float4 t;
    float* tp = &t.x;
#pragma unroll
    for (int k = 0; k < 4; ++k) {
      const int j = 4*c + k;
      const bool act = xs[j] > tau0;        // same predicate, same order
      const unsigned long long mk = __ballot(act);
      float v = 0.0f;
      if (act) v = cval[wid][base + __popcll(mk & ((1ull << lane) - 1ull))];
      base += __popcll(mk);
      tp[k] = v;
    }
    reinterpret_cast<float4*>(orow)[c * 64 + lane] = t;
  }
}

extern "C" void kernel_launch(void* const* d_in, const int* in_sizes, int n_in,
                              void* d_out, int out_size, void* d_ws, size_t ws_size,
                              hipStream_t stream) {
  const float* X = (const float*)d_in[0];
  const float* A = (const float*)d_in[1];
  float* O       = (float*)d_out;
  const int nrows = in_sizes[0] / 1024;                 // 65536
  const int blocks = (nrows + 3) / 4;                   // 4 rows (waves) per block
  hipLaunchKernelGGL(entmax_twoside, dim3(blocks), dim3(256), 0, stream,
                     X, A, O, nrows);
}

// Round 7
// 128.944 us; speedup vs baseline: 1.0363x; 1.0363x over previous
//
#include <hip/hip_runtime.h>

// alpha-entmax: bracketed POWER-LAW Newton on f(tau) = sum (xs-tau)_+^p,
// p = 1/(alpha-1), over the ballot-compacted fixed active set.
//   Model f ~ C*(m-tau)^q with q = p*g*(m-tau)/f  (g = sum u^(p-1));
//   solve C*(m-t)^q = 1  =>  m - tnew = (m-tau)*f^(-1/q).
//   = Newton in (log f) vs (log(m-tau)): 2nd-order at the root, EXACT for
//   single-dominant and equal-element rows, near-exact for dense Gaussian
//   heads (the expensive K=16 ones) where plain/F-Newton needed 4-6 evals.
//   f>1: step moves right toward root; f<1: f^(-1/q)>1 moves left -> no
//   R4-style stall. Bracket [tlo,thi] by sign(f-1); outside -> bisect.
// Active set {j: xs[j] > max-1} is FIXED (tau >= max-1 at all eval points),
// compacted to K=ceil(nact/64) elems/lane under a wave-uniform loop bound.
// Epilogue: normalized p written once to LDS, gathered by redoing the
// deterministic ballot over live xs[] regs -> coalesced float4 store.

__device__ __forceinline__ float wave_sum(float v) {
#pragma unroll
  for (int off = 32; off > 0; off >>= 1) v += __shfl_xor(v, off, 64);
  return v;
}
__device__ __forceinline__ float wave_max(float v) {
#pragma unroll
  for (int off = 32; off > 0; off >>= 1) v = fmaxf(v, __shfl_xor(v, off, 64));
  return v;
}

#define MAXIT 12

__global__ __launch_bounds__(256) void entmax_plnewton(
    const float* __restrict__ X, const float* __restrict__ A,
    float* __restrict__ O, int nrows) {
  __shared__ float cval[4][1024];   // compacted values; reused for normalized p

  const int lane = threadIdx.x & 63;
  const int wid  = threadIdx.x >> 6;
  const long long row = (long long)blockIdx.x * 4 + wid;
  if (row >= nrows) return;

  const float* xr = X + row * 1024;
  float* orow     = O + row * 1024;

  const int h = (int)((row >> 10) & 15);     // [B,H,Q] flattened, Q=1024
  const float a   = 1.01f + 0.98f * A[h];
  const float am1 = a - 1.0f;                // = 1/p
  const float inv = 1.0f / am1;              // = p in (1.01, 100]
  const float c1  = inv - 1.0f;

  // load row, scale by (alpha-1); element 4c+k of lane l = row[c*256 + l*4 + k]
  float xs[16];
#pragma unroll
  for (int c = 0; c < 4; ++c) {
    float4 t = reinterpret_cast<const float4*>(xr)[c * 64 + lane];
    xs[4*c+0] = t.x * am1; xs[4*c+1] = t.y * am1;
    xs[4*c+2] = t.z * am1; xs[4*c+3] = t.w * am1;
  }
  float m = xs[0];
#pragma unroll
  for (int j = 1; j < 16; ++j) m = fmaxf(m, xs[j]);
  m = wave_max(m);
  const float tau0 = m - 1.0f;

  // ---- ballot-compact the fixed active set {xs > tau0} into LDS ----
  int base = 0;
#pragma unroll
  for (int c = 0; c < 4; ++c) {
#pragma unroll
    for (int k = 0; k < 4; ++k) {
      const int j = 4*c + k;
      const bool act = xs[j] > tau0;
      const unsigned long long mk = __ballot(act);
      if (act)
        cval[wid][base + __popcll(mk & ((1ull << lane) - 1ull))] = xs[j];
      base += __popcll(mk);
    }
  }
  const int nact = __builtin_amdgcn_readfirstlane(base);   // >= 1 (the max)
  const int K    = (nact + 63) >> 6;                       // elems per lane
  for (int pos = nact + lane; pos < (K << 6); pos += 64)
    cval[wid][pos] = -3.0e38f;                             // pad: u == 0 forever
  asm volatile("s_waitcnt lgkmcnt(0)" ::: "memory");

  float vals[16];
#pragma unroll
  for (int k = 0; k < 16; ++k)
    if (k < K) vals[k] = cval[wid][lane + (k << 6)];

  // ---- bracketed power-law Newton ----
  float tlo = tau0;                                        // f(tlo) >= 1
  float thi = m - __builtin_amdgcn_exp2f(-10.0f * inv);    // f(thi) <= 1
  float tau = tau0;
  float p[16];
  float f = 1.0f;

  for (int it = 0; it < MAXIT; ++it) {
    float fs = 0.0f, gs = 0.0f;
#pragma unroll
    for (int k = 0; k < 16; ++k)
      if (k < K) {                                    // wave-uniform branch
        float u  = fmaxf(vals[k] - tau, 0.0f);
        float l  = __builtin_amdgcn_logf(u);          // log2(0) = -inf
        float e  = __builtin_amdgcn_exp2f(c1 * l);    // u^(p-1); exp2(-inf)=0
        float pe = e * u;                             // u^p
        p[k] = pe; fs += pe; gs += e;
      }
    f = wave_sum(fs);
    const float g = wave_sum(gs);

    float tnew;
    if (f > 0.0f) {
      if (f > 1.0f) tlo = tau; else thi = tau;        // bracket update
      if (fabsf(f - 1.0f) <= 1e-6f) break;            // at root; p,f consistent
      const float w  = m - tau;                       // in (0, 1]
      const float q  = inv * g * w / f;               // effective exponent > 0
      const float lf = __builtin_amdgcn_logf(f);      // log2 f
      const float fac = __builtin_amdgcn_exp2f(-lf / q);  // f^(-1/q)
      tnew = m - w * fac;
      if (!(tnew > tlo) || !(tnew < thi))             // out of bracket -> bisect
        tnew = 0.5f * (tlo + thi);
    } else {                                          // f underflowed to 0
      thi = tau;
      tnew = 0.5f * (tlo + thi);
    }
    const float delta = fabsf(tnew - tau);
    tau = tnew;
    if (!(delta > 1e-7f * fmaxf(fabsf(tau), 1.0f))) break;  // wave-uniform
  }

  // ---- epilogue: write normalized p, gather via recomputed positions ----
  const float r = 1.0f / f;                 // sum(p[]) == f from the last eval
#pragma unroll
  for (int k = 0; k < 16; ++k)
    if (k < K) cval[wid][lane + (k << 6)] = p[k] * r;
  asm volatile("s_waitcnt lgkmcnt(0)" ::: "memory");

  base = 0;
#pragma unroll
  for (int c = 0; c < 4; ++c) {
    float4 t;
    float* tp = &t.x;
#pragma unroll
    for (int k = 0; k < 4; ++k) {
      const int j = 4*c + k;
      const bool act = xs[j] > tau0;        // same predicate, same order
      const unsigned long long mk = __ballot(act);
      float v = 0.0f;
      if (act) v = cval[wid][base + __popcll(mk & ((1ull << lane) - 1ull))];
      base += __popcll(mk);
      tp[k] = v;
    }
    reinterpret_cast<float4*>(orow)[c * 64 + lane] = t;
  }
}

extern "C" void kernel_launch(void* const* d_in, const int* in_sizes, int n_in,
                              void* d_out, int out_size, void* d_ws, size_t ws_size,
                              hipStream_t stream) {
  const float* X = (const float*)d_in[0];
  const float* A = (const float*)d_in[1];
  float* O       = (float*)d_out;
  const int nrows = in_sizes[0] / 1024;                 // 65536
  const int blocks = (nrows + 3) / 4;                   // 4 rows (waves) per block
  hipLaunchKernelGGL(entmax_plnewton, dim3(blocks), dim3(256), 0, stream,
                     X, A, O, nrows);
}

// Round 8
// 117.380 us; speedup vs baseline: 1.1384x; 1.0985x over previous
//
#include <hip/hip_runtime.h>

// alpha-entmax, F-Newton (F = ||(xs-tau)_+||_p, p = 1/(alpha-1)) with
// active-set compaction (R3 structure — best known: 120.9 us), with ONE
// change: exit tolerance 1e-7 -> 8e-6. Error budget: |dP| <= p*dtau <= 100 *
// 2.4e-5 = 2.4e-3 added error vs threshold 2e-2. Saves the ~2-3 quadratic-tail
// evaluations (steps 1e-4 -> 1e-8) the old tol forced on every row.
//   tau monotone from tau0 = max-1 -> active set {xs > tau0} FIXED;
//   ballot-compact to K=ceil(nact/64) elems/lane; wave-uniform K-loop.
// Epilogue: zero LDS row, scatter normalized p by cidx, coalesced store.

__device__ __forceinline__ float wave_sum(float v) {
#pragma unroll
  for (int off = 32; off > 0; off >>= 1) v += __shfl_xor(v, off, 64);
  return v;
}
__device__ __forceinline__ float wave_max(float v) {
#pragma unroll
  for (int off = 32; off > 0; off >>= 1) v = fmaxf(v, __shfl_xor(v, off, 64));
  return v;
}

#define MAXIT 12

__global__ __launch_bounds__(256) void entmax_fnewton2(
    const float* __restrict__ X, const float* __restrict__ A,
    float* __restrict__ O, int nrows) {
  __shared__ float          cval[4][1024];  // compacted values; reused as p-row
  __shared__ unsigned short cidx[4][1024];  // compacted row positions

  const int lane = threadIdx.x & 63;
  const int wid  = threadIdx.x >> 6;
  const long long row = (long long)blockIdx.x * 4 + wid;
  if (row >= nrows) return;

  const float* xr = X + row * 1024;
  float* orow     = O + row * 1024;

  const int h = (int)((row >> 10) & 15);     // [B,H,Q] flattened, Q=1024
  const float a   = 1.01f + 0.98f * A[h];
  const float am1 = a - 1.0f;                // = 1/p
  const float inv = 1.0f / am1;              // = p in (1.01, 100]
  const float c1  = inv - 1.0f;

  // load row, scale by (alpha-1); element 4c+k of lane l = row[c*256 + l*4 + k]
  float xs[16];
#pragma unroll
  for (int c = 0; c < 4; ++c) {
    float4 t = reinterpret_cast<const float4*>(xr)[c * 64 + lane];
    xs[4*c+0] = t.x * am1; xs[4*c+1] = t.y * am1;
    xs[4*c+2] = t.z * am1; xs[4*c+3] = t.w * am1;
  }
  float m = xs[0];
#pragma unroll
  for (int j = 1; j < 16; ++j) m = fmaxf(m, xs[j]);
  m = wave_max(m);
  const float tau0 = m - 1.0f;

  // ---- ballot-compact the fixed active set into LDS ----
  int base = 0;
#pragma unroll
  for (int c = 0; c < 4; ++c) {
#pragma unroll
    for (int k = 0; k < 4; ++k) {
      const int j = 4*c + k;
      const bool act = xs[j] > tau0;
      const unsigned long long mk = __ballot(act);
      if (act) {
        const int pos = base + __popcll(mk & ((1ull << lane) - 1ull));
        cval[wid][pos] = xs[j];
        cidx[wid][pos] = (unsigned short)(c * 256 + lane * 4 + k);
      }
      base += __popcll(mk);
    }
  }
  const int nact = __builtin_amdgcn_readfirstlane(base);   // >= 1 (the max)
  const int K    = (nact + 63) >> 6;                       // elems per lane
  for (int pos = nact + lane; pos < (K << 6); pos += 64)
    cval[wid][pos] = -3.0e38f;                             // pad: u == 0 forever
  asm volatile("s_waitcnt lgkmcnt(0)" ::: "memory");

  float vals[16];
#pragma unroll
  for (int k = 0; k < 16; ++k)
    if (k < K) vals[k] = cval[wid][lane + (k << 6)];

  // ---- F-Newton (monotone from the f>=1 side) ----
  float tau = tau0;
  float p[16];
  float f = 1.0f;
  for (int it = 0; it < MAXIT; ++it) {
    float fs = 0.0f, gs = 0.0f;
#pragma unroll
    for (int k = 0; k < 16; ++k)
      if (k < K) {                                    // wave-uniform branch
        float u  = fmaxf(vals[k] - tau, 0.0f);
        float l  = __builtin_amdgcn_logf(u);          // log2(0) = -inf
        float e  = __builtin_amdgcn_exp2f(c1 * l);    // u^(p-1); exp2(-inf)=0
        float pe = e * u;                             // u^p
        p[k] = pe; fs += pe; gs += e;
      }
    f = wave_sum(fs);
    const float g = wave_sum(gs);
    if (!(g > 0.0f) || !(f > 0.0f)) break;
    if (fabsf(f - 1.0f) <= 1e-6f) break;              // exact hit
    const float lf = __builtin_amdgcn_logf(f);
    const float F  = __builtin_amdgcn_exp2f(am1 * lf); // f^(1/p)
    float step = (F - 1.0f) * f / (F * g);             // Newton on F-1
    step = fmaxf(step, 0.0f);                          // monotone; roundoff guard
    tau += step;
    // LOOSENED exit: dtau <= 8e-6*|tau| -> output err <= p*dtau ~ 2.4e-3 max
    if (!(step > 8e-6f * fmaxf(fabsf(tau), 1.0f))) break;  // wave-uniform
  }

  // ---- zero row in LDS, scatter normalized p, coalesced store ----
  const float r = 1.0f / f;
  const float4 z = make_float4(0.0f, 0.0f, 0.0f, 0.0f);
#pragma unroll
  for (int c = 0; c < 4; ++c)
    reinterpret_cast<float4*>(&cval[wid][0])[c * 64 + lane] = z;
  asm volatile("s_waitcnt lgkmcnt(0)" ::: "memory");
#pragma unroll
  for (int k = 0; k < 16; ++k)
    if (k < K) {
      const int pos = lane + (k << 6);
      if (pos < nact) cval[wid][cidx[wid][pos]] = p[k] * r;
    }
  asm volatile("s_waitcnt lgkmcnt(0)" ::: "memory");
#pragma unroll
  for (int c = 0; c < 4; ++c) {
    float4 t = reinterpret_cast<const float4*>(&cval[wid][0])[c * 64 + lane];
    reinterpret_cast<float4*>(orow)[c * 64 + lane] = t;
  }
}

extern "C" void kernel_launch(void* const* d_in, const int* in_sizes, int n_in,
                              void* d_out, int out_size, void* d_ws, size_t ws_size,
                              hipStream_t stream) {
  const float* X = (const float*)d_in[0];
  const float* A = (const float*)d_in[1];
  float* O       = (float*)d_out;
  const int nrows = in_sizes[0] / 1024;                 // 65536
  const int blocks = (nrows + 3) / 4;                   // 4 rows (waves) per block
  hipLaunchKernelGGL(entmax_fnewton2, dim3(blocks), dim3(256), 0, stream,
                     X, A, O, nrows);
}

// Round 9
// 111.875 us; speedup vs baseline: 1.1945x; 1.0492x over previous
//
#include <hip/hip_runtime.h>

// alpha-entmax: log-log SECANT on f(w) = sum (zs + w)_+^p, w = m - tau,
// zs = xs - m <= 0, p = 1/(alpha-1). Root f(w*) = 1, f increasing in w.
//   Model: log2 f linear in log2 w (power law; exact for single-dominant and
//   equal-element rows — R6's model, slope from the PREVIOUS EVAL instead of
//   from g). Needs only f per eval: NO g accumulation, ONE wave reduction,
//   one exp+log per element. First step (slope = p) == F-Newton step.
//   Safeguards: log-domain bracket [lwlo,lwhi] = [-10*am1, 0] (w* >= d^(-1/p)),
//   geometric bisection fallback, f-underflow -> bisect. MAXIT 12.
// Active set {zs > -1} FIXED (tau >= m-1 at all eval points), ballot-compacted;
// nact==1024 rows (the expensive dense ones) skip LDS/scatter entirely.

__device__ __forceinline__ float wave_sum(float v) {
#pragma unroll
  for (int off = 32; off > 0; off >>= 1) v += __shfl_xor(v, off, 64);
  return v;
}
__device__ __forceinline__ float wave_max(float v) {
#pragma unroll
  for (int off = 32; off > 0; off >>= 1) v = fmaxf(v, __shfl_xor(v, off, 64));
  return v;
}

#define MAXIT 12

__global__ __launch_bounds__(256) void entmax_secant(
    const float* __restrict__ X, const float* __restrict__ A,
    float* __restrict__ O, int nrows) {
  __shared__ float          cval[4][1024];  // compacted zs; reused as p-row
  __shared__ unsigned short cidx[4][1024];  // compacted row positions

  const int lane = threadIdx.x & 63;
  const int wid  = threadIdx.x >> 6;
  const long long row = (long long)blockIdx.x * 4 + wid;
  if (row >= nrows) return;

  const float* xr = X + row * 1024;
  float* orow     = O + row * 1024;

  const int h = (int)((row >> 10) & 15);     // [B,H,Q] flattened, Q=1024
  const float a   = 1.01f + 0.98f * A[h];
  const float am1 = a - 1.0f;                // = 1/p
  const float inv = 1.0f / am1;              // = p in (1.01, 100]

  // load row, scale by (alpha-1); element 4c+k of lane l = row[c*256 + l*4 + k]
  float xs[16];
#pragma unroll
  for (int c = 0; c < 4; ++c) {
    float4 t = reinterpret_cast<const float4*>(xr)[c * 64 + lane];
    xs[4*c+0] = t.x * am1; xs[4*c+1] = t.y * am1;
    xs[4*c+2] = t.z * am1; xs[4*c+3] = t.w * am1;
  }
  float m = xs[0];
#pragma unroll
  for (int j = 1; j < 16; ++j) m = fmaxf(m, xs[j]);
  m = wave_max(m);
#pragma unroll
  for (int j = 0; j < 16; ++j) xs[j] -= m;   // zs <= 0; active iff zs > -1

  // ---- ballot-count / compact the fixed active set ----
  int base = 0;
#pragma unroll
  for (int c = 0; c < 4; ++c) {
#pragma unroll
    for (int k = 0; k < 4; ++k) {
      const int j = 4*c + k;
      const bool act = xs[j] > -1.0f;
      const unsigned long long mk = __ballot(act);
      if (act) {
        const int pos = base + __popcll(mk & ((1ull << lane) - 1ull));
        cval[wid][pos] = xs[j];
        cidx[wid][pos] = (unsigned short)(c * 256 + lane * 4 + k);
      }
      base += __popcll(mk);
    }
  }
  const int nact   = __builtin_amdgcn_readfirstlane(base); // >= 1
  const bool direct = (nact == 1024);                      // dense fast path
  int K;
  float vals[16];
  if (direct) {
    K = 16;
#pragma unroll
    for (int k = 0; k < 16; ++k) vals[k] = xs[k];
  } else {
    K = (nact + 63) >> 6;
    for (int pos = nact + lane; pos < (K << 6); pos += 64)
      cval[wid][pos] = -2.0f;                              // pad: never active
    asm volatile("s_waitcnt lgkmcnt(0)" ::: "memory");
#pragma unroll
    for (int k = 0; k < 16; ++k)
      if (k < K) vals[k] = cval[wid][lane + (k << 6)];
  }

  // ---- log-log secant ----
  float lwlo = -10.0f * am1;   // log2(d^(-1/p)): provable lower bracket
  float lwhi = 0.0f;
  float w = 1.0f, lw = 0.0f;
  float lw_p = 0.0f, lf_p = 0.0f;            // previous (lw, lf) sample
  float p[16];
  float f = 1.0f;

  for (int it = 0; it < MAXIT; ++it) {
    float fs = 0.0f;
#pragma unroll
    for (int k = 0; k < 16; ++k)
      if (k < K) {                                     // wave-uniform bound
        float u  = fmaxf(vals[k] + w, 0.0f);
        float pe = __builtin_amdgcn_exp2f(
            inv * __builtin_amdgcn_logf(u));           // u^p; log2(0)=-inf->0
        p[k] = pe; fs += pe;
      }
    f = wave_sum(fs);

    float lwnew;
    if (f > 0.0f) {
      if (fabsf(f - 1.0f) <= 1e-6f) break;             // exact hit
      const float lf = __builtin_amdgcn_logf(f);       // log2 f
      if (f > 1.0f) lwhi = lw; else lwlo = lw;         // bracket update
      // inverse slope: first step uses 1/p (== F-Newton step), then secant
      const float si = (it == 0) ? am1 : (lw - lw_p) / (lf - lf_p);
      lw_p = lw; lf_p = lf;
      lwnew = lw - lf * si;
      if (!(si > 0.0f) || !(lwnew > lwlo) || !(lwnew < lwhi))
        lwnew = 0.5f * (lwlo + lwhi);                  // geometric bisect
    } else {                                           // f underflowed to 0
      lwlo = lw;                                       // w below the root
      lwnew = 0.5f * (lwlo + lwhi);
    }
    const float wnew  = __builtin_amdgcn_exp2f(lwnew);
    const float delta = fabsf(wnew - w);
    // |dP| <= p*dtau, dtau = dw: same 8e-6 budget as R7
    if (!(delta > 8e-6f * fmaxf(fabsf(m - w), 1.0f))) break;
    w = wnew; lw = lwnew;
  }

  // ---- epilogue ----
  const float r = 1.0f / f;                  // sum(p[]) == f from last eval
  if (direct) {                              // positions are identity
#pragma unroll
    for (int c = 0; c < 4; ++c) {
      float4 t;
      t.x = p[4*c+0] * r; t.y = p[4*c+1] * r;
      t.z = p[4*c+2] * r; t.w = p[4*c+3] * r;
      reinterpret_cast<float4*>(orow)[c * 64 + lane] = t;
    }
  } else {                                   // zero row, scatter, gather, store
    const float4 z = make_float4(0.0f, 0.0f, 0.0f, 0.0f);
#pragma unroll
    for (int c = 0; c < 4; ++c)
      reinterpret_cast<float4*>(&cval[wid][0])[c * 64 + lane] = z;
    asm volatile("s_waitcnt lgkmcnt(0)" ::: "memory");
#pragma unroll
    for (int k = 0; k < 16; ++k)
      if (k < K) {
        const int pos = lane + (k << 6);
        if (pos < nact) cval[wid][cidx[wid][pos]] = p[k] * r;
      }
    asm volatile("s_waitcnt lgkmcnt(0)" ::: "memory");
#pragma unroll
    for (int c = 0; c < 4; ++c) {
      float4 t = reinterpret_cast<const float4*>(&cval[wid][0])[c * 64 + lane];
      reinterpret_cast<float4*>(orow)[c * 64 + lane] = t;
    }
  }
}

extern "C" void kernel_launch(void* const* d_in, const int* in_sizes, int n_in,
                              void* d_out, int out_size, void* d_ws, size_t ws_size,
                              hipStream_t stream) {
  const float* X = (const float*)d_in[0];
  const float* A = (const float*)d_in[1];
  float* O       = (float*)d_out;
  const int nrows = in_sizes[0] / 1024;                 // 65536
  const int blocks = (nrows + 3) / 4;                   // 4 rows (waves) per block
  hipLaunchKernelGGL(entmax_secant, dim3(blocks), dim3(256), 0, stream,
                     X, A, O, nrows);
}

// Round 10
// 99.161 us; speedup vs baseline: 1.3476x; 1.1282x over previous
//
#include <hip/hip_runtime.h>

// alpha-entmax: log-log secant (R8 solver) + DPP cross-lane reductions +
// count-first dense fast path + it0 power-law seed.
//   f(w) = sum (zs + w)_+^p, zs = xs - m <= 0, p = 1/(alpha-1); root f = 1.
//   it0 (w=1): accumulate g = sum u^(p-1) too; exact local power exponent
//   q0 = p*g/f -> lw1 = -lf/q0. Then secant in (log2 w, log2 f). Bracket
//   [-10*am1, 0] + geometric bisection fallback; f-underflow -> bisect.
// Reductions: DPP (quad_perm/mirrors + row_bcast15/31 + readlane 63) — 6
// full-rate VALU ops instead of 6 LDS-pipe shuffles.
// Rows with K == 16 never touch LDS (original-order solve, identity layout).

template <int CTRL, int RM>
__device__ __forceinline__ float dpp_add(float x) {
  int s = __builtin_amdgcn_update_dpp(0, __builtin_bit_cast(int, x),
                                      CTRL, RM, 0xF, false);
  return x + __builtin_bit_cast(float, s);
}
template <int CTRL, int RM>
__device__ __forceinline__ float dpp_max(float x) {
  int s = __builtin_amdgcn_update_dpp((int)0xFF800000,
                                      __builtin_bit_cast(int, x),
                                      CTRL, RM, 0xF, false);
  return fmaxf(x, __builtin_bit_cast(float, s));
}
// returns wave-uniform (sgpr) total
__device__ __forceinline__ float wave_sum(float x) {
  x = dpp_add<0xB1, 0xF>(x);    // quad_perm [1,0,3,2]  (xor 1)
  x = dpp_add<0x4E, 0xF>(x);    // quad_perm [2,3,0,1]  (xor 2)
  x = dpp_add<0x141, 0xF>(x);   // row_half_mirror      (xor 4)
  x = dpp_add<0x140, 0xF>(x);   // row_mirror           (xor 8)
  x = dpp_add<0x142, 0xA>(x);   // row_bcast15 -> rows 1,3
  x = dpp_add<0x143, 0xC>(x);   // row_bcast31 -> rows 2,3
  return __builtin_bit_cast(float,
      __builtin_amdgcn_readlane(__builtin_bit_cast(int, x), 63));
}
__device__ __forceinline__ float wave_max(float x) {
  x = dpp_max<0xB1, 0xF>(x);
  x = dpp_max<0x4E, 0xF>(x);
  x = dpp_max<0x141, 0xF>(x);
  x = dpp_max<0x140, 0xF>(x);
  x = dpp_max<0x142, 0xA>(x);
  x = dpp_max<0x143, 0xC>(x);
  return __builtin_bit_cast(float,
      __builtin_amdgcn_readlane(__builtin_bit_cast(int, x), 63));
}

#define MAXIT 12

__global__ __launch_bounds__(256) void entmax_dpp(
    const float* __restrict__ X, const float* __restrict__ A,
    float* __restrict__ O, int nrows) {
  __shared__ float          cval[4][1024];
  __shared__ unsigned short cidx[4][1024];

  const int lane = threadIdx.x & 63;
  const int wid  = threadIdx.x >> 6;
  const long long row = (long long)blockIdx.x * 4 + wid;
  if (row >= nrows) return;

  const float* xr = X + row * 1024;
  float* orow     = O + row * 1024;

  const int h = (int)((row >> 10) & 15);     // [B,H,Q] flattened, Q=1024
  const float a   = 1.01f + 0.98f * A[h];
  const float am1 = a - 1.0f;                // = 1/p
  const float inv = 1.0f / am1;              // = p in (1.01, 100]
  const float c1  = inv - 1.0f;

  float xs[16];
#pragma unroll
  for (int c = 0; c < 4; ++c) {
    float4 t = reinterpret_cast<const float4*>(xr)[c * 64 + lane];
    xs[4*c+0] = t.x * am1; xs[4*c+1] = t.y * am1;
    xs[4*c+2] = t.z * am1; xs[4*c+3] = t.w * am1;
  }
  float m = xs[0];
#pragma unroll
  for (int j = 1; j < 16; ++j) m = fmaxf(m, xs[j]);
  m = wave_max(m);
#pragma unroll
  for (int j = 0; j < 16; ++j) xs[j] -= m;   // zs <= 0; active iff zs > -1

  // ---- count-first (all-scalar accumulate; nact is wave-uniform) ----
  int nact = 0;
#pragma unroll
  for (int j = 0; j < 16; ++j)
    nact += (int)__popcll(__ballot(xs[j] > -1.0f));
  const int  K      = (nact + 63) >> 6;
  const bool direct = (K == 16);             // dense: solve in original order

  float vals[16];
  if (direct) {
#pragma unroll
    for (int k = 0; k < 16; ++k) vals[k] = xs[k];
  } else {
    int base = 0;
#pragma unroll
    for (int c = 0; c < 4; ++c) {
#pragma unroll
      for (int k = 0; k < 4; ++k) {
        const int j = 4*c + k;
        const bool act = xs[j] > -1.0f;
        const unsigned long long mk = __ballot(act);
        if (act) {
          const int pos = base + __popcll(mk & ((1ull << lane) - 1ull));
          cval[wid][pos] = xs[j];
          cidx[wid][pos] = (unsigned short)(c * 256 + lane * 4 + k);
        }
        base += __popcll(mk);
      }
    }
    for (int pos = nact + lane; pos < (K << 6); pos += 64)
      cval[wid][pos] = -2.0f;                // pad: never active
    asm volatile("s_waitcnt lgkmcnt(0)" ::: "memory");
#pragma unroll
    for (int k = 0; k < 16; ++k)
      if (k < K) vals[k] = cval[wid][lane + (k << 6)];
  }

  // ---- it0: eval at w=1 with g; exact local power-law step ----
  float lwlo = -10.0f * am1;                 // log2(d^(-1/p)) lower bracket
  float lwhi = 0.0f;
  float w = 1.0f, lw = 0.0f;
  float p[16];
  float f, lw_p, lf_p;
  {
    float fs = 0.0f, gs = 0.0f;
#pragma unroll
    for (int k = 0; k < 16; ++k)
      if (k < K) {
        float u  = fmaxf(vals[k] + 1.0f, 0.0f);
        float e  = __builtin_amdgcn_exp2f(c1 * __builtin_amdgcn_logf(u));
        float pe = e * u;
        p[k] = pe; fs += pe; gs += e;
      }
    f = wave_sum(fs);
    const float g = wave_sum(gs);            // g >= 1 (max elem), f >= 1
    lw_p = 0.0f; lf_p = __builtin_amdgcn_logf(f);
    if (fabsf(f - 1.0f) > 1e-6f) {
      // q0 = p*g*w/f (w=1); lw1 = lw - lf/q0
      float lwn = -lf_p * f * am1 / g;
      if (!(lwn > lwlo) || !(lwn < lwhi)) lwn = 0.5f * (lwlo + lwhi);
      lwhi = 0.0f;  lwlo = fmaxf(lwlo, -10.0f * am1);
      lwhi = fminf(lwhi, lw);                // f(1) >= 1 -> root at lw <= 0
      w = __builtin_amdgcn_exp2f(lwn); lw = lwn;

      // ---- secant iterations (f only) ----
      for (int it = 1; it < MAXIT; ++it) {
        float fs2 = 0.0f;
#pragma unroll
        for (int k = 0; k < 16; ++k)
          if (k < K) {
            float u  = fmaxf(vals[k] + w, 0.0f);
            float pe = __builtin_amdgcn_exp2f(
                inv * __builtin_amdgcn_logf(u));
            p[k] = pe; fs2 += pe;
          }
        f = wave_sum(fs2);

        float lwnew;
        if (f > 0.0f) {
          if (fabsf(f - 1.0f) <= 1e-6f) break;
          const float lf = __builtin_amdgcn_logf(f);
          if (f > 1.0f) lwhi = lw; else lwlo = lw;
          const float si = (lw - lw_p) / (lf - lf_p);   // inverse slope
          lw_p = lw; lf_p = lf;
          lwnew = lw - lf * si;
          if (!(si > 0.0f) || !(lwnew > lwlo) || !(lwnew < lwhi))
            lwnew = 0.5f * (lwlo + lwhi);
        } else {                              // underflow: w below root
          lwlo = lw;
          lwnew = 0.5f * (lwlo + lwhi);
        }
        const float wnew  = __builtin_amdgcn_exp2f(lwnew);
        const float delta = fabsf(wnew - w);
        if (!(delta > 8e-6f * fmaxf(fabsf(m - w), 1.0f))) break;
        w = wnew; lw = lwnew;
      }
    }
  }

  // ---- epilogue: sum(p[]) == f from the last eval ----
  const float r = 1.0f / f;
  if (direct) {                               // identity layout
#pragma unroll
    for (int c = 0; c < 4; ++c) {
      float4 t;
      t.x = p[4*c+0] * r; t.y = p[4*c+1] * r;
      t.z = p[4*c+2] * r; t.w = p[4*c+3] * r;
      reinterpret_cast<float4*>(orow)[c * 64 + lane] = t;
    }
  } else {                                    // zero, scatter by cidx, store
    const float4 z = make_float4(0.0f, 0.0f, 0.0f, 0.0f);
#pragma unroll
    for (int c = 0; c < 4; ++c)
      reinterpret_cast<float4*>(&cval[wid][0])[c * 64 + lane] = z;
    asm volatile("s_waitcnt lgkmcnt(0)" ::: "memory");
#pragma unroll
    for (int k = 0; k < 16; ++k)
      if (k < K) {
        const int pos = lane + (k << 6);
        if (pos < nact) cval[wid][cidx[wid][pos]] = p[k] * r;
      }
    asm volatile("s_waitcnt lgkmcnt(0)" ::: "memory");
#pragma unroll
    for (int c = 0; c < 4; ++c) {
      float4 t = reinterpret_cast<const float4*>(&cval[wid][0])[c * 64 + lane];
      reinterpret_cast<float4*>(orow)[c * 64 + lane] = t;
    }
  }
}

extern "C" void kernel_launch(void* const* d_in, const int* in_sizes, int n_in,
                              void* d_out, int out_size, void* d_ws, size_t ws_size,
                              hipStream_t stream) {
  const float* X = (const float*)d_in[0];
  const float* A = (const float*)d_in[1];
  float* O       = (float*)d_out;
  const int nrows = in_sizes[0] / 1024;                 // 65536
  const int blocks = (nrows + 3) / 4;                   // 4 rows (waves) per block
  hipLaunchKernelGGL(entmax_dpp, dim3(blocks), dim3(256), 0, stream,
                     X, A, O, nrows);
}

// Round 11
// 93.934 us; speedup vs baseline: 1.4226x; 1.0556x over previous
//
#include <hip/hip_runtime.h>

// alpha-entmax: log-log IQI/secant solver + DPP reductions + count-first
// dense fast path + it0 power-law seed + nontemporal streaming.
//   f(w) = sum (zs + w)_+^p, zs = xs - m <= 0, p = 1/(alpha-1); root f = 1.
//   it0 (w=1): also accumulate g -> exact local power exponent q0 = p*g/f,
//   seed lw1 = -lf0/q0 (== F-Newton). Then inverse-quadratic interpolation
//   in (log2 f -> log2 w) on the last 3 points (order ~1.84), bracket
//   [-10*am1, 0] + secant + geometric-bisection fallbacks; underflow->bisect.
// Reductions: DPP (quad_perm/mirrors + row_bcast15/31 + readlane 63).
// Rows with K == 16 never touch LDS (original-order solve, identity layout).

typedef float f4 __attribute__((ext_vector_type(4)));

template <int CTRL, int RM>
__device__ __forceinline__ float dpp_add(float x) {
  int s = __builtin_amdgcn_update_dpp(0, __builtin_bit_cast(int, x),
                                      CTRL, RM, 0xF, false);
  return x + __builtin_bit_cast(float, s);
}
template <int CTRL, int RM>
__device__ __forceinline__ float dpp_max(float x) {
  int s = __builtin_amdgcn_update_dpp((int)0xFF800000,
                                      __builtin_bit_cast(int, x),
                                      CTRL, RM, 0xF, false);
  return fmaxf(x, __builtin_bit_cast(float, s));
}
__device__ __forceinline__ float wave_sum(float x) {
  x = dpp_add<0xB1, 0xF>(x);    // quad_perm xor1
  x = dpp_add<0x4E, 0xF>(x);    // quad_perm xor2
  x = dpp_add<0x141, 0xF>(x);   // row_half_mirror (xor4)
  x = dpp_add<0x140, 0xF>(x);   // row_mirror (xor8)
  x = dpp_add<0x142, 0xA>(x);   // row_bcast15 -> rows 1,3
  x = dpp_add<0x143, 0xC>(x);   // row_bcast31 -> rows 2,3
  return __builtin_bit_cast(float,
      __builtin_amdgcn_readlane(__builtin_bit_cast(int, x), 63));
}
__device__ __forceinline__ float wave_max(float x) {
  x = dpp_max<0xB1, 0xF>(x);
  x = dpp_max<0x4E, 0xF>(x);
  x = dpp_max<0x141, 0xF>(x);
  x = dpp_max<0x140, 0xF>(x);
  x = dpp_max<0x142, 0xA>(x);
  x = dpp_max<0x143, 0xC>(x);
  return __builtin_bit_cast(float,
      __builtin_amdgcn_readlane(__builtin_bit_cast(int, x), 63));
}

#define MAXIT 12

__global__ __launch_bounds__(256) void entmax_iqi(
    const float* __restrict__ X, const float* __restrict__ A,
    float* __restrict__ O, int nrows) {
  __shared__ float          cval[4][1024];
  __shared__ unsigned short cidx[4][1024];

  const int lane = threadIdx.x & 63;
  const int wid  = threadIdx.x >> 6;
  const long long row = (long long)blockIdx.x * 4 + wid;
  if (row >= nrows) return;

  const f4* xr4 = reinterpret_cast<const f4*>(X + row * 1024);
  f4* or4       = reinterpret_cast<f4*>(O + row * 1024);

  const int h = (int)((row >> 10) & 15);     // [B,H,Q] flattened, Q=1024
  const float a   = 1.01f + 0.98f * A[h];
  const float am1 = a - 1.0f;                // = 1/p
  const float inv = 1.0f / am1;              // = p in (1.01, 100]
  const float c1  = inv - 1.0f;

  float xs[16];
#pragma unroll
  for (int c = 0; c < 4; ++c) {
    f4 t = __builtin_nontemporal_load(xr4 + c * 64 + lane);
    xs[4*c+0] = t.x * am1; xs[4*c+1] = t.y * am1;
    xs[4*c+2] = t.z * am1; xs[4*c+3] = t.w * am1;
  }
  float m = xs[0];
#pragma unroll
  for (int j = 1; j < 16; ++j) m = fmaxf(m, xs[j]);
  m = wave_max(m);
#pragma unroll
  for (int j = 0; j < 16; ++j) xs[j] -= m;   // zs <= 0; active iff zs > -1

  // ---- count-first (nact wave-uniform) ----
  int nact = 0;
#pragma unroll
  for (int j = 0; j < 16; ++j)
    nact += (int)__popcll(__ballot(xs[j] > -1.0f));
  const int  K      = (nact + 63) >> 6;
  const bool direct = (K == 16);             // dense: solve in original order

  float vals[16];
  if (direct) {
#pragma unroll
    for (int k = 0; k < 16; ++k) vals[k] = xs[k];
  } else {
    int base = 0;
#pragma unroll
    for (int c = 0; c < 4; ++c) {
#pragma unroll
      for (int k = 0; k < 4; ++k) {
        const int j = 4*c + k;
        const bool act = xs[j] > -1.0f;
        const unsigned long long mk = __ballot(act);
        if (act) {
          const int pos = base + __popcll(mk & ((1ull << lane) - 1ull));
          cval[wid][pos] = xs[j];
          cidx[wid][pos] = (unsigned short)(c * 256 + lane * 4 + k);
        }
        base += __popcll(mk);
      }
    }
    for (int pos = nact + lane; pos < (K << 6); pos += 64)
      cval[wid][pos] = -2.0f;                // pad: never active
    asm volatile("s_waitcnt lgkmcnt(0)" ::: "memory");
#pragma unroll
    for (int k = 0; k < 16; ++k)
      if (k < K) vals[k] = cval[wid][lane + (k << 6)];
  }

  // ---- it0: eval at w=1 with g; exact local power-law seed ----
  float lwlo = -10.0f * am1;                 // log2(d^(-1/p)) lower bracket
  float lwhi = 0.0f;
  float w = 1.0f, lw = 0.0f;
  float p[16];
  float f, lw_p, lf_p;
  float lw_pp = 0.0f, lf_pp = 0.0f;
  bool have2 = false;
  {
    float fs = 0.0f, gs = 0.0f;
#pragma unroll
    for (int k = 0; k < 16; ++k)
      if (k < K) {
        float u  = fmaxf(vals[k] + 1.0f, 0.0f);
        float e  = __builtin_amdgcn_exp2f(c1 * __builtin_amdgcn_logf(u));
        float pe = e * u;
        p[k] = pe; fs += pe; gs += e;
      }
    f = wave_sum(fs);
    const float g = wave_sum(gs);            // g >= 1, f >= 1 at w=1
    lw_p = 0.0f; lf_p = __builtin_amdgcn_logf(f);
    if (fabsf(f - 1.0f) > 1e-6f) {
      // q0 = p*g*w/f (w=1); lw1 = -lf0/q0
      float lwn = -lf_p * f * am1 / g;
      if (!(lwn > lwlo) || !(lwn < lwhi)) lwn = 0.5f * (lwlo + lwhi);
      w = __builtin_amdgcn_exp2f(lwn); lw = lwn;

      // ---- IQI / secant iterations (f only) ----
      for (int it = 1; it < MAXIT; ++it) {
        float fs2 = 0.0f;
#pragma unroll
        for (int k = 0; k < 16; ++k)
          if (k < K) {
            float u  = fmaxf(vals[k] + w, 0.0f);
            float pe = __builtin_amdgcn_exp2f(
                inv * __builtin_amdgcn_logf(u));
            p[k] = pe; fs2 += pe;
          }
        f = wave_sum(fs2);

        float lwnew;
        if (f > 0.0f) {
          if (fabsf(f - 1.0f) <= 1e-6f) break;
          const float lf = __builtin_amdgcn_logf(f);
          if (f > 1.0f) lwhi = lw; else lwlo = lw;

          float cand = 0.0f; bool got = false;
          if (have2) {
            // inverse quadratic interpolation to lf = 0
            const float d01 = lf - lf_p, d02 = lf - lf_pp, d12 = lf_p - lf_pp;
            const float r01 = __builtin_amdgcn_rcpf(d01);
            const float r02 = __builtin_amdgcn_rcpf(d02);
            const float r12 = __builtin_amdgcn_rcpf(d12);
            cand = lw    * lf_p * lf_pp * r01 * r02
                 - lw_p  * lf   * lf_pp * r01 * r12
                 + lw_pp * lf   * lf_p  * r02 * r12;
            got = (cand > lwlo) && (cand < lwhi);   // inf/nan fail here
          }
          if (!got) {
            const float si = (lw - lw_p) / (lf - lf_p); // secant
            cand = lw - lf * si;
            if (!(si > 0.0f) || !(cand > lwlo) || !(cand < lwhi))
              cand = 0.5f * (lwlo + lwhi);            // geometric bisect
          }
          lw_pp = lw_p; lf_pp = lf_p; lw_p = lw; lf_p = lf; have2 = true;
          lwnew = cand;
        } else {                              // underflow: w below root
          lwlo = lw;
          lwnew = 0.5f * (lwlo + lwhi);
        }
        const float wnew  = __builtin_amdgcn_exp2f(lwnew);
        // |dP| <= p*dtau; tol 2e-5 rel adds <= ~6e-3 worst-case (thr 2e-2)
        if (!(fabsf(wnew - w) > 2e-5f * fmaxf(fabsf(m - w), 1.0f))) break;
        w = wnew; lw = lwnew;
      }
    }
  }

  // ---- epilogue: sum(p[]) == f from the last eval ----
  const float r = 1.0f / f;
  if (direct) {                               // identity layout
#pragma unroll
    for (int c = 0; c < 4; ++c) {
      f4 t;
      t.x = p[4*c+0] * r; t.y = p[4*c+1] * r;
      t.z = p[4*c+2] * r; t.w = p[4*c+3] * r;
      __builtin_nontemporal_store(t, or4 + c * 64 + lane);
    }
  } else {                                    // zero, scatter by cidx, store
    const f4 z = {0.0f, 0.0f, 0.0f, 0.0f};
#pragma unroll
    for (int c = 0; c < 4; ++c)
      reinterpret_cast<f4*>(&cval[wid][0])[c * 64 + lane] = z;
    asm volatile("s_waitcnt lgkmcnt(0)" ::: "memory");
#pragma unroll
    for (int k = 0; k < 16; ++k)
      if (k < K) {
        const int pos = lane + (k << 6);
        if (pos < nact) cval[wid][cidx[wid][pos]] = p[k] * r;
      }
    asm volatile("s_waitcnt lgkmcnt(0)" ::: "memory");
#pragma unroll
    for (int c = 0; c < 4; ++c) {
      f4 t = reinterpret_cast<const f4*>(&cval[wid][0])[c * 64 + lane];
      __builtin_nontemporal_store(t, or4 + c * 64 + lane);
    }
  }
}

extern "C" void kernel_launch(void* const* d_in, const int* in_sizes, int n_in,
                              void* d_out, int out_size, void* d_ws, size_t ws_size,
                              hipStream_t stream) {
  const float* X = (const float*)d_in[0];
  const float* A = (const float*)d_in[1];
  float* O       = (float*)d_out;
  const int nrows = in_sizes[0] / 1024;                 // 65536
  const int blocks = (nrows + 3) / 4;                   // 4 rows (waves) per block
  hipLaunchKernelGGL(entmax_iqi, dim3(blocks), dim3(256), 0, stream,
                     X, A, O, nrows);
}